// Round 1
// baseline (249.447 us; speedup 1.0000x reference)
//
#include <hip/hip_runtime.h>

#define EPS 1e-5f

// native vector type (accepted by __builtin_nontemporal_store)
typedef float nfloat4 __attribute__((ext_vector_type(4)));

// B=8, T=8192, C=512 fixed by setup_inputs().

// K1: per-frame channel sum + sumsq. One wave per frame (C=512 -> 2 float4
// per lane), shuffle reduce. Pure HBM-read bound (128 MiB).
__global__ __launch_bounds__(256) void frame_stats_kernel(
    const float* __restrict__ x, float* __restrict__ s_arr,
    float* __restrict__ q_arr) {
  const int wave = threadIdx.x >> 6;
  const int lane = threadIdx.x & 63;
  const int frame = blockIdx.x * 4 + wave;
  const nfloat4* xb = (const nfloat4*)(x + (size_t)frame * 512);
  nfloat4 a = xb[lane];       // floats [0,256)
  nfloat4 b = xb[64 + lane];  // floats [256,512)
  float s = a.x + a.y + a.z + a.w + b.x + b.y + b.z + b.w;
  float q = a.x * a.x + a.y * a.y + a.z * a.z + a.w * a.w +
            b.x * b.x + b.y * b.y + b.z * b.z + b.w * b.w;
#pragma unroll
  for (int off = 32; off >= 1; off >>= 1) {
    s += __shfl_down(s, off);
    q += __shfl_down(q, off);
  }
  if (lane == 0) {
    s_arr[frame] = s;
    q_arr[frame] = q;
  }
}

// K2: per-row coupled scan -> per-frame mean & rsqrt(var+eps).
// 8 blocks (one per batch row) x 1024 threads, 8 frames/thread.
// Runs ONCE per row (was redundantly repeated by all 64 apply blocks).
// Reads 64 KiB stats/row from L2, writes 512 KiB mean/inv total.
__global__ __launch_bounds__(1024) void row_scan_kernel(
    const float* __restrict__ s_arr, const float* __restrict__ q_arr,
    float* __restrict__ mean_arr, float* __restrict__ inv_arr) {
  const int T = 8192;
  const int tid = threadIdx.x;
  const int lane = tid & 63;
  const int wid = tid >> 6;  // 16 waves
  const int b = blockIdx.x;  // batch row

  __shared__ float lds_s[16];
  __shared__ float lds_v[16];

  const nfloat4* s4p = (const nfloat4*)(s_arr + (size_t)b * T);
  const nfloat4* q4p = (const nfloat4*)(q_arr + (size_t)b * T);

  nfloat4 sa = s4p[2 * tid];
  nfloat4 sb = s4p[2 * tid + 1];
  nfloat4 qa = q4p[2 * tid];
  nfloat4 qb = q4p[2 * tid + 1];

  // scan of s
  float p0 = sa.x;
  float p1 = p0 + sa.y;
  float p2 = p1 + sa.z;
  float p3 = p2 + sa.w;
  float p4 = p3 + sb.x;
  float p5 = p4 + sb.y;
  float p6 = p5 + sb.z;
  float p7 = p6 + sb.w;
  float tot = p7, incl = tot;
#pragma unroll
  for (int off = 1; off < 64; off <<= 1) {
    float n = __shfl_up(incl, off);
    if (lane >= off) incl += n;
  }
  if (lane == 63) lds_s[wid] = incl;
  __syncthreads();
  float waveExcl = 0.f;
#pragma unroll
  for (int wv = 0; wv < 16; ++wv)
    if (wv < wid) waveExcl += lds_s[wv];
  float base = waveExcl + incl - tot;

  const int t0 = tid << 3;  // first frame owned by this thread
  float c0 = (float)(t0 + 1) * 512.f;
  float c1 = (float)(t0 + 2) * 512.f;
  float c2 = (float)(t0 + 3) * 512.f;
  float c3 = (float)(t0 + 4) * 512.f;
  float c4 = (float)(t0 + 5) * 512.f;
  float c5 = (float)(t0 + 6) * 512.f;
  float c6 = (float)(t0 + 7) * 512.f;
  float c7 = (float)(t0 + 8) * 512.f;
  float m0 = (base + p0) / c0;
  float m1 = (base + p1) / c1;
  float m2 = (base + p2) / c2;
  float m3 = (base + p3) / c3;
  float m4 = (base + p4) / c4;
  float m5 = (base + p5) / c5;
  float m6 = (base + p6) / c6;
  float m7 = (base + p7) / c7;

  // per-frame squared-deviation sum: q - 2*m*s + C*m^2
  float v0 = qa.x - 2.f * m0 * sa.x + 512.f * m0 * m0;
  float v1 = qa.y - 2.f * m1 * sa.y + 512.f * m1 * m1;
  float v2 = qa.z - 2.f * m2 * sa.z + 512.f * m2 * m2;
  float v3 = qa.w - 2.f * m3 * sa.w + 512.f * m3 * m3;
  float v4 = qb.x - 2.f * m4 * sb.x + 512.f * m4 * m4;
  float v5 = qb.y - 2.f * m5 * sb.y + 512.f * m5 * m5;
  float v6 = qb.z - 2.f * m6 * sb.z + 512.f * m6 * m6;
  float v7 = qb.w - 2.f * m7 * sb.w + 512.f * m7 * m7;

  // scan of v
  float r0 = v0;
  float r1 = r0 + v1;
  float r2 = r1 + v2;
  float r3 = r2 + v3;
  float r4 = r3 + v4;
  float r5 = r4 + v5;
  float r6 = r5 + v6;
  float r7 = r6 + v7;
  float totv = r7, inclv = totv;
#pragma unroll
  for (int off = 1; off < 64; off <<= 1) {
    float n = __shfl_up(inclv, off);
    if (lane >= off) inclv += n;
  }
  if (lane == 63) lds_v[wid] = inclv;
  __syncthreads();
  float waveExclV = 0.f;
#pragma unroll
  for (int wv = 0; wv < 16; ++wv)
    if (wv < wid) waveExclV += lds_v[wv];
  float baseV = waveExclV + inclv - totv;

  nfloat4 mlo, mhi, ilo, ihi;
  mlo.x = m0; mlo.y = m1; mlo.z = m2; mlo.w = m3;
  mhi.x = m4; mhi.y = m5; mhi.z = m6; mhi.w = m7;
  ilo.x = rsqrtf((baseV + r0) / c0 + EPS);
  ilo.y = rsqrtf((baseV + r1) / c1 + EPS);
  ilo.z = rsqrtf((baseV + r2) / c2 + EPS);
  ilo.w = rsqrtf((baseV + r3) / c3 + EPS);
  ihi.x = rsqrtf((baseV + r4) / c4 + EPS);
  ihi.y = rsqrtf((baseV + r5) / c5 + EPS);
  ihi.z = rsqrtf((baseV + r6) / c6 + EPS);
  ihi.w = rsqrtf((baseV + r7) / c7 + EPS);

  nfloat4* mrow = (nfloat4*)(mean_arr + (size_t)b * T);
  nfloat4* irow = (nfloat4*)(inv_arr + (size_t)b * T);
  mrow[2 * tid] = mlo;
  mrow[2 * tid + 1] = mhi;
  irow[2 * tid] = ilo;
  irow[2 * tid + 1] = ihi;
}

// K3: pure streaming apply. 2048 blocks x 256 threads, each block owns 32
// consecutive global frames (32*512 floats = 4096 float4, 16/thread).
// Low VGPR -> 8 blocks/CU -> the whole grid is resident (2048 = 8*256CU):
// no tranche tail, no scan preamble. x re-read is L3-warm from K1; out is
// write-only -> nontemporal store keeps x resident in L3.
__global__ __launch_bounds__(256) void apply_kernel(
    const float* __restrict__ x, const float* __restrict__ w,
    const float* __restrict__ mean_arr, const float* __restrict__ inv_arr,
    float* __restrict__ out) {
  const int tid = threadIdx.x;
  __shared__ float lds_m[32];
  __shared__ float lds_i[32];
  const int f0 = blockIdx.x << 5;  // global frame base (b*8192+t is linear)
  if (tid < 32) {
    lds_m[tid] = mean_arr[f0 + tid];
    lds_i[tid] = inv_arr[f0 + tid];
  }
  __syncthreads();

  // channel float4 index = (k*256 + tid) & 127 = tid & 127 (k stride is 256)
  const nfloat4 wv4 = ((const nfloat4*)w)[tid & 127];
  const size_t base4 = (size_t)f0 << 7;  // 128 float4 per frame
  const nfloat4* x4 = (const nfloat4*)x;
  nfloat4* out4 = (nfloat4*)out;
#pragma unroll 4
  for (int k = 0; k < 16; ++k) {
    const size_t idx = base4 + (size_t)(k << 8) + (size_t)tid;
    const int fl = (k << 1) + (tid >> 7);  // local frame 0..31
    nfloat4 xv = x4[idx];
    const float m = lds_m[fl];
    const float iv = lds_i[fl];
    nfloat4 o;
    o.x = (xv.x - m) * iv * wv4.x;
    o.y = (xv.y - m) * iv * wv4.y;
    o.z = (xv.z - m) * iv * wv4.z;
    o.w = (xv.w - m) * iv * wv4.w;
    __builtin_nontemporal_store(o, out4 + idx);
  }
}

extern "C" void kernel_launch(void* const* d_in, const int* in_sizes, int n_in,
                              void* d_out, int out_size, void* d_ws,
                              size_t ws_size, hipStream_t stream) {
  const float* x = (const float*)d_in[0];
  const float* w = (const float*)d_in[1];
  float* out = (float*)d_out;
  const int BT = 65536;

  float* s_arr = (float*)d_ws;       // BT floats
  float* q_arr = s_arr + BT;         // BT floats
  float* mean_arr = q_arr + BT;      // BT floats
  float* inv_arr = mean_arr + BT;    // BT floats

  frame_stats_kernel<<<BT / 4, 256, 0, stream>>>(x, s_arr, q_arr);
  row_scan_kernel<<<8, 1024, 0, stream>>>(s_arr, q_arr, mean_arr, inv_arr);
  apply_kernel<<<BT / 32, 256, 0, stream>>>(x, w, mean_arr, inv_arr, out);
}